// Round 1
// baseline (377.847 us; speedup 1.0000x reference)
//
#include <hip/hip_runtime.h>

#define B_   4
#define CIN  32
#define COUT 32
#define NN   81920
#define KK   10

// ---------- Kernel 1: transpose input (B, C, N) -> xT (B, N, C) ----------
__global__ __launch_bounds__(256) void k_transpose(const float* __restrict__ in,
                                                   float* __restrict__ xT) {
    __shared__ float tile[32][65];   // +1 pad -> conflict-free both phases
    const int b  = blockIdx.y;
    const int n0 = blockIdx.x * 64;
    const int tid = threadIdx.x;

    // Load phase: each wave reads one c-row of 64 consecutive n (256 B coalesced)
#pragma unroll
    for (int i = 0; i < 8; ++i) {
        const int c = i * 4 + (tid >> 6);
        const int n = tid & 63;
        tile[c][n] = in[((size_t)b * CIN + c) * NN + n0 + n];
    }
    __syncthreads();
    // Store phase: lanes 0..31 write 32 consecutive c (128 B coalesced per n)
#pragma unroll
    for (int i = 0; i < 8; ++i) {
        const int n = i * 8 + (tid >> 5);
        const int c = tid & 31;
        xT[((size_t)b * NN + n0 + n) * CIN + c] = tile[c][n];
    }
}

// ---------- Kernel 2: rearrange weight (O, C, K, 1) -> wr[k][o][c] ----------
__global__ void k_wrearrange(const float* __restrict__ w, float* __restrict__ wr) {
    const int i = blockIdx.x * 256 + threadIdx.x;
    if (i < COUT * CIN * KK) {
        const int k = i / (COUT * CIN);
        const int r = i % (COUT * CIN);
        const int o = r / CIN;
        const int c = r % CIN;
        wr[i] = w[((size_t)o * CIN + c) * KK + k];
    }
}

// ---------- Kernel 3: main gathered conv ----------
// One thread per (b, n). 32 fp32 accumulators; weights broadcast via SGPR
// (uniform addresses -> s_load); x gathered as 8x float4 (128 B/lane).
__global__ __launch_bounds__(256) void k_main(const float* __restrict__ xT,
                                              const float* __restrict__ wr,
                                              const float* __restrict__ bias,
                                              const int* __restrict__ tbl,
                                              float* __restrict__ out) {
    const int tid = threadIdx.x;
    const int nb  = blockIdx.x % (NN / 256);
    const int b   = blockIdx.x / (NN / 256);
    const int n   = nb * 256 + tid;

    float acc[COUT];
#pragma unroll
    for (int o = 0; o < COUT; ++o) acc[o] = bias[o];

    for (int k = 0; k < KK; ++k) {
        const int t = tbl[(size_t)k * NN + n];          // coalesced across lanes
        const float4* xp = (const float4*)(xT + ((size_t)b * NN + t) * CIN);
        float4 xv[8];
#pragma unroll
        for (int j = 0; j < 8; ++j) xv[j] = xp[j];      // 128 B gather per lane
        const float* x  = (const float*)xv;
        const float* wk = wr + (size_t)k * COUT * CIN;  // uniform -> s_load
#pragma unroll
        for (int o = 0; o < COUT; ++o) {
#pragma unroll
            for (int c = 0; c < CIN; ++c)
                acc[o] = fmaf(x[c], wk[o * CIN + c], acc[o]);
        }
    }

#pragma unroll
    for (int o = 0; o < COUT; ++o) {
        const float v = acc[o];
        out[((size_t)(b * COUT + o)) * NN + n] = v > 0.f ? v : 0.f;  // ReLU
    }
}

extern "C" void kernel_launch(void* const* d_in, const int* in_sizes, int n_in,
                              void* d_out, int out_size, void* d_ws, size_t ws_size,
                              hipStream_t stream) {
    const float* inp  = (const float*)d_in[0];
    const float* w    = (const float*)d_in[1];
    const float* bias = (const float*)d_in[2];
    const int*   tbl  = (const int*)d_in[3];
    // d_in[4] = stride (always 1 for this problem)

    float* xT = (float*)d_ws;                                   // 41.94 MB
    float* wr = (float*)((char*)d_ws + (size_t)B_ * NN * CIN * sizeof(float));
    float* out = (float*)d_out;

    k_transpose<<<dim3(NN / 64, B_), 256, 0, stream>>>(inp, xT);
    k_wrearrange<<<(COUT * CIN * KK + 255) / 256, 256, 0, stream>>>(w, wr);
    k_main<<<B_ * NN / 256, 256, 0, stream>>>(xT, wr, bias, tbl, out);
}

// Round 2
// 56.863 us; speedup vs baseline: 6.6449x; 6.6449x over previous
//
#include <hip/hip_runtime.h>
#include <stdint.h>

#define B_   4
#define CIN  32
#define COUT 32
#define NN   81920
#define KK   10
#define NT   128          // n-tile per block

typedef unsigned short ushort_t;
typedef __attribute__((ext_vector_type(8))) short bf16x8;
typedef __attribute__((ext_vector_type(4))) float f32x4;

// float -> bf16 bits, round-to-nearest-even
__device__ __host__ __forceinline__ ushort_t f2bf(float f) {
    union { float f; unsigned int u; } v; v.f = f;
    unsigned int r = (v.u + 0x7FFFu + ((v.u >> 16) & 1u)) >> 16;
    return (ushort_t)r;
}

__device__ __forceinline__ void gl_lds16(const void* g, void* lds) {
    auto gp = (const __attribute__((address_space(1))) unsigned int*)((uintptr_t)g);
    auto lp = (__attribute__((address_space(3))) unsigned int*)((uintptr_t)lds);
    __builtin_amdgcn_global_load_lds(gp, lp, 16, 0, 0);
}

// ---------- Kernel 1: transpose+convert input (B, C, N) f32 -> xb (B, N, C) bf16 ----------
__global__ __launch_bounds__(256) void k_transpose(const float* __restrict__ in,
                                                   ushort_t* __restrict__ xb) {
    __shared__ float tile[32][65];
    const int b   = blockIdx.y;
    const int n0  = blockIdx.x * 64;
    const int tid = threadIdx.x;

#pragma unroll
    for (int i = 0; i < 8; ++i) {
        const int c = i * 4 + (tid >> 6);
        const int n = tid & 63;
        tile[c][n] = in[((size_t)b * CIN + c) * NN + n0 + n];
    }
    __syncthreads();
    // 64 n x 16 c-pairs; lane writes 2 channels packed as one dword
#pragma unroll
    for (int i = 0; i < 4; ++i) {
        const int n  = i * 16 + (tid >> 4);
        const int cp = tid & 15;
        const unsigned int u0 = f2bf(tile[2 * cp][n]);
        const unsigned int u1 = f2bf(tile[2 * cp + 1][n]);
        *(unsigned int*)&xb[((size_t)b * NN + n0 + n) * CIN + 2 * cp] = u0 | (u1 << 16);
    }
}

// ---------- Kernel 2: weight (O, C, K, 1) f32 -> wb[o][ck] bf16, ck = k*32 + c ----------
__global__ void k_wprep(const float* __restrict__ w, ushort_t* __restrict__ wb) {
    const int i = blockIdx.x * 256 + threadIdx.x;
    if (i < COUT * CIN * KK) {
        const int o = i / (CIN * KK);
        const int ck = i % (CIN * KK);
        const int k = ck >> 5, c = ck & 31;
        wb[i] = f2bf(w[((size_t)o * CIN + c) * KK + k]);
    }
}

// ---------- Kernel 3: gathered conv as MFMA GEMM ----------
// out[b,o,n] = relu( sum_{ck} W[o,ck] * xb[b, tbl[k,n], c] + bias[o] )
__global__ __launch_bounds__(256) void k_main(const ushort_t* __restrict__ xb,
                                              const ushort_t* __restrict__ wb,
                                              const float* __restrict__ bias,
                                              const int* __restrict__ tbl,
                                              float* __restrict__ out) {
    __shared__ ushort_t Wl[COUT][328];        // pad 320->328: conflict-free A-reads
    __shared__ ushort_t Xl[2][NT][CIN];       // 64 B rows: conflict-free writes+reads

    const int tid = threadIdx.x;
    const int bid = blockIdx.x;
    // XCD swizzle: batch b owns XCD pair {2b,2b+1} -> per-XCD gather set ~5.2 MB
    const int b    = (bid & 7) >> 1;
    const int tile = (bid >> 3) * 2 + (bid & 1);
    const int n0   = tile * NT;

    for (int idx = tid; idx < COUT * CIN * KK; idx += 256)
        Wl[idx / 320][idx % 320] = wb[idx];

    const int lane = tid & 63;
    const int wid  = tid >> 6;
    const int wn   = wid * 32;       // wave's n-offset within tile
    const int lr   = lane & 15;
    const int lg   = lane >> 4;

    f32x4 acc[2][2];
#pragma unroll
    for (int m = 0; m < 2; ++m) {
        f32x4 bv;
#pragma unroll
        for (int r = 0; r < 4; ++r) bv[r] = bias[m * 16 + lg * 4 + r];
        acc[m][0] = bv; acc[m][1] = bv;
    }

    const size_t xbase = (size_t)b * NN * CIN;

    // stage k=0 into buffer 0 (4 lanes per gather point, 16 B each, lane-linear LDS)
#pragma unroll
    for (int half = 0; half < 2; ++half) {
        const int j = tid + half * 256;
        const int i = j >> 2, q = j & 3;
        const int t = tbl[n0 + i];
        gl_lds16(xb + xbase + (size_t)t * CIN + q * 8, &Xl[0][i][q * 8]);
    }
    asm volatile("s_waitcnt vmcnt(0)" ::: "memory");
    __syncthreads();

    for (int k = 0; k < KK; ++k) {
        const int cur = k & 1;
        if (k + 1 < KK) {
#pragma unroll
            for (int half = 0; half < 2; ++half) {
                const int j = tid + half * 256;
                const int i = j >> 2, q = j & 3;
                const int t = tbl[(size_t)(k + 1) * NN + n0 + i];
                gl_lds16(xb + xbase + (size_t)t * CIN + q * 8, &Xl[cur ^ 1][i][q * 8]);
            }
        }
        const bf16x8 a0 = *(const bf16x8*)&Wl[lr][k * 32 + lg * 8];
        const bf16x8 a1 = *(const bf16x8*)&Wl[16 + lr][k * 32 + lg * 8];
        const bf16x8 b0 = *(const bf16x8*)&Xl[cur][wn + lr][lg * 8];
        const bf16x8 b1 = *(const bf16x8*)&Xl[cur][wn + 16 + lr][lg * 8];
        acc[0][0] = __builtin_amdgcn_mfma_f32_16x16x32_bf16(a0, b0, acc[0][0], 0, 0, 0);
        acc[1][0] = __builtin_amdgcn_mfma_f32_16x16x32_bf16(a1, b0, acc[1][0], 0, 0, 0);
        acc[0][1] = __builtin_amdgcn_mfma_f32_16x16x32_bf16(a0, b1, acc[0][1], 0, 0, 0);
        acc[1][1] = __builtin_amdgcn_mfma_f32_16x16x32_bf16(a1, b1, acc[1][1], 0, 0, 0);

        asm volatile("s_waitcnt vmcnt(0)" ::: "memory");
        __syncthreads();
    }

#pragma unroll
    for (int m = 0; m < 2; ++m)
#pragma unroll
        for (int nt = 0; nt < 2; ++nt)
#pragma unroll
            for (int r = 0; r < 4; ++r) {
                const int o = m * 16 + lg * 4 + r;
                const int n = n0 + wn + nt * 16 + lr;
                const float v = acc[m][nt][r];
                out[((size_t)(b * COUT + o)) * NN + n] = v > 0.f ? v : 0.f;
            }
}

extern "C" void kernel_launch(void* const* d_in, const int* in_sizes, int n_in,
                              void* d_out, int out_size, void* d_ws, size_t ws_size,
                              hipStream_t stream) {
    const float* inp  = (const float*)d_in[0];
    const float* w    = (const float*)d_in[1];
    const float* bias = (const float*)d_in[2];
    const int*   tbl  = (const int*)d_in[3];

    ushort_t* xb = (ushort_t*)d_ws;                              // 20.97 MB
    ushort_t* wb = (ushort_t*)((char*)d_ws + (size_t)B_ * NN * CIN * sizeof(ushort_t));
    float* out = (float*)d_out;

    k_transpose<<<dim3(NN / 64, B_), 256, 0, stream>>>(inp, xb);
    k_wprep<<<(COUT * CIN * KK + 255) / 256, 256, 0, stream>>>(w, wb);
    k_main<<<B_ * (NN / NT), 256, 0, stream>>>(xb, wb, bias, tbl, out);
}

// Round 3
// 53.229 us; speedup vs baseline: 7.0985x; 1.0683x over previous
//
#include <hip/hip_runtime.h>
#include <stdint.h>

#define B_   4
#define CIN  32
#define COUT 32
#define NN   81920
#define KK   10
#define NT   128          // n-tile per block
#define PF   4            // LDS X buffers (3-deep prefetch)

typedef unsigned short ushort_t;
typedef __attribute__((ext_vector_type(8))) short bf16x8;
typedef __attribute__((ext_vector_type(4))) float f32x4;

// float -> bf16 bits, round-to-nearest-even
__device__ __host__ __forceinline__ ushort_t f2bf(float f) {
    union { float f; unsigned int u; } v; v.f = f;
    unsigned int r = (v.u + 0x7FFFu + ((v.u >> 16) & 1u)) >> 16;
    return (ushort_t)r;
}

__device__ __forceinline__ void gl_lds16(const void* g, void* lds) {
    auto gp = (const __attribute__((address_space(1))) unsigned int*)((uintptr_t)g);
    auto lp = (__attribute__((address_space(3))) unsigned int*)((uintptr_t)lds);
    __builtin_amdgcn_global_load_lds(gp, lp, 16, 0, 0);
}

// ---------- Kernel 1: transpose+convert input (B, C, N) f32 -> xb (B, N, C) bf16 ----------
__global__ __launch_bounds__(256) void k_transpose(const float* __restrict__ in,
                                                   ushort_t* __restrict__ xb) {
    __shared__ float tile[32][65];
    const int b   = blockIdx.y;
    const int n0  = blockIdx.x * 64;
    const int tid = threadIdx.x;

#pragma unroll
    for (int i = 0; i < 8; ++i) {
        const int c = i * 4 + (tid >> 6);
        const int n = tid & 63;
        tile[c][n] = in[((size_t)b * CIN + c) * NN + n0 + n];
    }
    __syncthreads();
#pragma unroll
    for (int i = 0; i < 4; ++i) {
        const int n  = i * 16 + (tid >> 4);
        const int cp = tid & 15;
        const unsigned int u0 = f2bf(tile[2 * cp][n]);
        const unsigned int u1 = f2bf(tile[2 * cp + 1][n]);
        *(unsigned int*)&xb[((size_t)b * NN + n0 + n) * CIN + 2 * cp] = u0 | (u1 << 16);
    }
}

// ---------- Kernel 2: weight (O, C, K, 1) f32 -> wb[o][ck] bf16, ck = k*32 + c ----------
__global__ void k_wprep(const float* __restrict__ w, ushort_t* __restrict__ wb) {
    const int i = blockIdx.x * 256 + threadIdx.x;
    if (i < COUT * CIN * KK) {
        const int o = i / (CIN * KK);
        const int ck = i % (CIN * KK);
        const int k = ck >> 5, c = ck & 31;
        wb[i] = f2bf(w[((size_t)o * CIN + c) * KK + k]);
    }
}

// ---------- Kernel 3: gathered conv as MFMA GEMM, 3-deep pipelined ----------
// LDS row swizzle: row i's four 16B chunks rotated by (i>>1)&3 (baked into the
// gather SOURCE address; dest stays lane-linear for global_load_lds).
__global__ __launch_bounds__(256) void k_main(const ushort_t* __restrict__ xb,
                                              const ushort_t* __restrict__ wb,
                                              const float* __restrict__ bias,
                                              const int* __restrict__ tbl,
                                              float* __restrict__ out) {
    __shared__ ushort_t Wl[COUT][328];        // pad 320->328: 2-way (free) A-reads
    __shared__ ushort_t Xl[PF][NT][CIN];      // 4 x 8KB double^2-buffer

    const int tid = threadIdx.x;
    const int bid = blockIdx.x;
    const int b    = (bid & 7) >> 1;          // batch -> XCD pair
    const int tile = (bid >> 3) * 2 + (bid & 1);
    const int n0   = tile * NT;

    for (int idx = tid; idx < COUT * CIN * KK; idx += 256)
        Wl[idx / 320][idx % 320] = wb[idx];

    const int lane = tid & 63;
    const int wid  = tid >> 6;
    const int wn   = wid * 32;
    const int lr   = lane & 15;
    const int lg   = lane >> 4;

    // staging geometry: lane tid covers (row i, LDS chunk-pos p); the logical
    // chunk at pos p of row i is (p - (i>>1)) & 3
    const int i_  = tid >> 2;
    const int p_  = tid & 3;
    const int q0_ = (p_ - (i_ >> 1)) & 3;
    const int i2_ = 64 + i_;
    const int q1_ = (p_ - (i2_ >> 1)) & 3;

    // preload ALL table entries (keeps vmcnt = pure gather count in the loop)
    int tpre0[KK], tpre1[KK];
#pragma unroll
    for (int k = 0; k < KK; ++k) {
        tpre0[k] = tbl[(size_t)k * NN + n0 + i_];
        tpre1[k] = tbl[(size_t)k * NN + n0 + i2_];
    }

    f32x4 acc[2][2];
#pragma unroll
    for (int m = 0; m < 2; ++m) {
        f32x4 bv;
#pragma unroll
        for (int r = 0; r < 4; ++r) bv[r] = bias[m * 16 + lg * 4 + r];
        acc[m][0] = bv; acc[m][1] = bv;
    }

    const size_t xbase = (size_t)b * NN * CIN;

#define STAGE(kk, buf)                                                          \
    do {                                                                        \
        gl_lds16(xb + xbase + (size_t)tpre0[kk] * CIN + q0_ * 8,                \
                 &Xl[buf][i_][p_ * 8]);                                         \
        gl_lds16(xb + xbase + (size_t)tpre1[kk] * CIN + q1_ * 8,                \
                 &Xl[buf][i2_][p_ * 8]);                                        \
    } while (0)

    // drain everything non-gather, make Wl visible, then prime 3 stages
    asm volatile("s_waitcnt vmcnt(0) lgkmcnt(0)" ::: "memory");
    __builtin_amdgcn_s_barrier();
    STAGE(0, 0);
    STAGE(1, 1);
    STAGE(2, 2);

#pragma unroll
    for (int k = 0; k < KK; ++k) {
        const int cur = k & (PF - 1);
        // counted wait: keep later stages in flight (2 loads per stage per thread)
        if (k < KK - 3)      asm volatile("s_waitcnt vmcnt(4) lgkmcnt(0)" ::: "memory");
        else if (k == KK - 3) asm volatile("s_waitcnt vmcnt(4) lgkmcnt(0)" ::: "memory");
        else if (k == KK - 2) asm volatile("s_waitcnt vmcnt(2) lgkmcnt(0)" ::: "memory");
        else                 asm volatile("s_waitcnt vmcnt(0) lgkmcnt(0)" ::: "memory");
        __builtin_amdgcn_s_barrier();

        if (k + 3 < KK) STAGE(k + 3, (k + 3) & (PF - 1));

        const int R0 = wn + lr, R1 = wn + 16 + lr;
        const bf16x8 a0 = *(const bf16x8*)&Wl[lr][k * 32 + lg * 8];
        const bf16x8 a1 = *(const bf16x8*)&Wl[16 + lr][k * 32 + lg * 8];
        const bf16x8 b0 = *(const bf16x8*)&Xl[cur][R0][((lg + (R0 >> 1)) & 3) * 8];
        const bf16x8 b1 = *(const bf16x8*)&Xl[cur][R1][((lg + (R1 >> 1)) & 3) * 8];
        acc[0][0] = __builtin_amdgcn_mfma_f32_16x16x32_bf16(a0, b0, acc[0][0], 0, 0, 0);
        acc[1][0] = __builtin_amdgcn_mfma_f32_16x16x32_bf16(a1, b0, acc[1][0], 0, 0, 0);
        acc[0][1] = __builtin_amdgcn_mfma_f32_16x16x32_bf16(a0, b1, acc[0][1], 0, 0, 0);
        acc[1][1] = __builtin_amdgcn_mfma_f32_16x16x32_bf16(a1, b1, acc[1][1], 0, 0, 0);
        __builtin_amdgcn_sched_barrier(0);   // pin MFMAs (+their lgkm waits) here
    }
#undef STAGE

#pragma unroll
    for (int m = 0; m < 2; ++m)
#pragma unroll
        for (int nt = 0; nt < 2; ++nt)
#pragma unroll
            for (int r = 0; r < 4; ++r) {
                const int o = m * 16 + lg * 4 + r;
                const int n = n0 + wn + nt * 16 + lr;
                const float v = acc[m][nt][r];
                out[((size_t)(b * COUT + o)) * NN + n] = v > 0.f ? v : 0.f;
            }
}

extern "C" void kernel_launch(void* const* d_in, const int* in_sizes, int n_in,
                              void* d_out, int out_size, void* d_ws, size_t ws_size,
                              hipStream_t stream) {
    const float* inp  = (const float*)d_in[0];
    const float* w    = (const float*)d_in[1];
    const float* bias = (const float*)d_in[2];
    const int*   tbl  = (const int*)d_in[3];

    ushort_t* xb = (ushort_t*)d_ws;                              // 20.97 MB
    ushort_t* wb = (ushort_t*)((char*)d_ws + (size_t)B_ * NN * CIN * sizeof(ushort_t));
    float* out = (float*)d_out;

    k_transpose<<<dim3(NN / 64, B_), 256, 0, stream>>>(inp, xb);
    k_wprep<<<(COUT * CIN * KK + 255) / 256, 256, 0, stream>>>(w, wb);
    k_main<<<B_ * (NN / NT), 256, 0, stream>>>(xb, wb, bias, tbl, out);
}